// Round 1
// baseline (1368.899 us; speedup 1.0000x reference)
//
#include <hip/hip_runtime.h>
#include <hip/hip_bf16.h>
#include <math.h>

#define CHUNK 16
#define NN 1764
#define SORTN 2048

// ---------------- weight transpose:  W[co][ci][k] -> Wt[(ci*9+k)][co] ----------------
template<int Co, int CiK>
__device__ inline void seg_tr(const float* __restrict__ src, float* __restrict__ dst, int i) {
  int co = i / CiK; int cik = i - co * CiK;
  dst[cik * Co + co] = src[i];
}

__global__ void wtrans_all(
  const float* __restrict__ b1w, const float* __restrict__ c1w,
  const float* __restrict__ b2w, const float* __restrict__ c2w,
  const float* __restrict__ b3w, const float* __restrict__ b4w,
  const float* __restrict__ c3w,
  float* __restrict__ wt1b, float* __restrict__ wt1c,
  float* __restrict__ wt2b, float* __restrict__ wt2c,
  float* __restrict__ wt3b, float* __restrict__ wt4b, float* __restrict__ wt3c)
{
  int j = blockIdx.x * blockDim.x + threadIdx.x;
  if (j < 1179648) { seg_tr<256, 4608>(b1w, wt1b, j); return; } j -= 1179648;
  if (j < 1179648) { seg_tr<256, 4608>(c1w, wt1c, j); return; } j -= 1179648;
  if (j < 294912)  { seg_tr<128, 2304>(b2w, wt2b, j); return; } j -= 294912;
  if (j < 294912)  { seg_tr<128, 2304>(c2w, wt2c, j); return; } j -= 294912;
  if (j < 147456)  { seg_tr<128, 1152>(b3w, wt3b, j); return; } j -= 147456;
  if (j < 4608)    { seg_tr<36, 128>(b4w, wt4b, j); return; }  j -= 4608;
  if (j < 1152)    { seg_tr<9, 128>(c3w, wt3c, j); return; }
}

// ---------------- fused conv3x3 + bias + GELU + GroupNorm(8ch groups) ----------------
// block: (batch, 16 out-channels = 2 groups). thread = 1 pixel (196 active of 256).
__global__ __launch_bounds__(256) void conv3x3_gn(
    const float* __restrict__ in0, const float* __restrict__ in1,
    const float* __restrict__ wt0, const float* __restrict__ wt1,
    const float* __restrict__ bs0, const float* __restrict__ bs1,
    const float* __restrict__ gw0, const float* __restrict__ gw1,
    const float* __restrict__ gb0, const float* __restrict__ gb1,
    float* __restrict__ out0, float* __restrict__ out1,
    int Cin, int Cout, int cobPerHead)
{
  const int tid = threadIdx.x;
  const int bx  = blockIdx.x;
  const int b   = blockIdx.y;
  const int head = bx / cobPerHead;
  const int cob  = bx - head * cobPerHead;
  const float* in  = head ? in1  : in0;
  const float* wt  = head ? wt1  : wt0;
  const float* bs  = head ? bs1  : bs0;
  const float* gw  = head ? gw1  : gw0;
  const float* gb  = head ? gb1  : gb0;
  float* out       = head ? out1 : out0;
  const int co0 = cob * 16;

  __shared__ float ls[CHUNK][256];
  __shared__ float red[4][4];
  __shared__ float stats[4];

  float acc[16];
#pragma unroll
  for (int c = 0; c < 16; ++c) acc[c] = bs[co0 + c];

  const int p = tid;
  const bool active = p < 196;
  const int py = p / 14, px = p - py * 14;
  const int base = py * 16 + px;          // halo tile index of (py-1,px-1) neighbor

  // staging coords: LDS cell tid = (ly,lx) in 16x16 halo <-> global (ly-1, lx-1)
  const int ly = tid >> 4, lx = tid & 15;
  const int gy = ly - 1, gx = lx - 1;
  const bool inr = (gy >= 0) && (gy < 14) && (gx >= 0) && (gx < 14);
  const int gidx = gy * 14 + gx;

  const float* inb = in + (size_t)b * Cin * 196;
  const int nch = Cin / CHUNK;

  for (int cb = 0; cb < nch; ++cb) {
    __syncthreads();
#pragma unroll
    for (int ci = 0; ci < CHUNK; ++ci) {
      ls[ci][tid] = inr ? inb[(cb * CHUNK + ci) * 196 + gidx] : 0.0f;
    }
    __syncthreads();
    if (active) {
      const float* wblk = wt + (size_t)(cb * CHUNK * 9) * Cout + co0;
      for (int ci = 0; ci < CHUNK; ++ci) {
        float n[9];
#pragma unroll
        for (int ky = 0; ky < 3; ++ky)
#pragma unroll
          for (int kx = 0; kx < 3; ++kx)
            n[ky * 3 + kx] = ls[ci][base + ky * 16 + kx];
        const float* w = wblk + (size_t)ci * 9 * Cout;
#pragma unroll
        for (int k = 0; k < 9; ++k) {
          const float* wr = w + k * Cout;   // wave-uniform -> s_load
#pragma unroll
          for (int c = 0; c < 16; ++c) acc[c] = fmaf(wr[c], n[k], acc[c]);
        }
      }
    }
  }

  // GELU (erf, exact) + per-group partial sums
  float s0 = 0.f, q0 = 0.f, s1 = 0.f, q1 = 0.f;
  if (active) {
#pragma unroll
    for (int c = 0; c < 16; ++c) {
      float v = acc[c];
      float g = 0.5f * v * (1.0f + erff(v * 0.70710678118654752440f));
      acc[c] = g;
      if (c < 8) { s0 += g; q0 += g * g; } else { s1 += g; q1 += g * g; }
    }
  }
  // wave reduce (64-wide) then cross-wave via LDS
#pragma unroll
  for (int off = 32; off > 0; off >>= 1) {
    s0 += __shfl_down(s0, off, 64); q0 += __shfl_down(q0, off, 64);
    s1 += __shfl_down(s1, off, 64); q1 += __shfl_down(q1, off, 64);
  }
  const int wave = tid >> 6, lane = tid & 63;
  __syncthreads();
  if (lane == 0) { red[wave][0] = s0; red[wave][1] = q0; red[wave][2] = s1; red[wave][3] = q1; }
  __syncthreads();
  if (tid == 0) {
    float S0 = red[0][0] + red[1][0] + red[2][0] + red[3][0];
    float Q0 = red[0][1] + red[1][1] + red[2][1] + red[3][1];
    float S1 = red[0][2] + red[1][2] + red[2][2] + red[3][2];
    float Q1 = red[0][3] + red[1][3] + red[2][3] + red[3][3];
    float m0 = S0 * (1.0f / 1568.0f);
    float v0 = Q0 * (1.0f / 1568.0f) - m0 * m0;
    float m1 = S1 * (1.0f / 1568.0f);
    float v1 = Q1 * (1.0f / 1568.0f) - m1 * m1;
    stats[0] = m0; stats[1] = 1.0f / sqrtf(v0 + 1e-5f);
    stats[2] = m1; stats[3] = 1.0f / sqrtf(v1 + 1e-5f);
  }
  __syncthreads();
  if (active) {
    float m0 = stats[0], i0 = stats[1], m1 = stats[2], i1 = stats[3];
#pragma unroll
    for (int c = 0; c < 16; ++c) {
      float m = (c < 8) ? m0 : m1;
      float iv = (c < 8) ? i0 : i1;
      float y = (acc[c] - m) * iv * gw[co0 + c] + gb[co0 + c];
      out[((size_t)b * Cout + co0 + c) * 196 + p] = y;
    }
  }
}

// ---------------- 1x1 heads: bbox (128->36) and cls (128->9, sigmoid) ----------------
__global__ __launch_bounds__(256) void heads_1x1(
    const float* __restrict__ tb, const float* __restrict__ tc,
    const float* __restrict__ wtb, const float* __restrict__ wtc, // [128][36], [128][9]
    const float* __restrict__ bb,  const float* __restrict__ bc,
    float* __restrict__ bbox, float* __restrict__ conf)
{
  const int b = blockIdx.x, tid = threadIdx.x;
  if (tid >= 196) return;
  const int p = tid;
  float ab[36], ac[9];
#pragma unroll
  for (int o = 0; o < 36; ++o) ab[o] = bb[o];
#pragma unroll
  for (int o = 0; o < 9; ++o) ac[o] = bc[o];
  const float* pb = tb + (size_t)b * 128 * 196 + p;
  const float* pc = tc + (size_t)b * 128 * 196 + p;
  for (int ci = 0; ci < 128; ++ci) {
    float xb = pb[ci * 196];
    float xc = pc[ci * 196];
    const float* wb = wtb + ci * 36;   // uniform -> s_load
    const float* wc = wtc + ci * 9;
#pragma unroll
    for (int o = 0; o < 36; ++o) ab[o] = fmaf(wb[o], xb, ab[o]);
#pragma unroll
    for (int o = 0; o < 9; ++o)  ac[o] = fmaf(wc[o], xc, ac[o]);
  }
  const size_t nb = (size_t)b * NN;
#pragma unroll
  for (int a = 0; a < 9; ++a) {
    size_t n = nb + (size_t)p * 9 + a;
#pragma unroll
    for (int d = 0; d < 4; ++d) bbox[n * 4 + d] = ab[a * 4 + d];
    conf[n] = 1.0f / (1.0f + expf(-ac[a]));
  }
}

// ---------------- per-image greedy NMS with early exit at 50 kept ----------------
__global__ __launch_bounds__(256) void nms_kernel(
  const float* __restrict__ bbox, const float* __restrict__ conf, float* __restrict__ out)
{
  const int b = blockIdx.x, tid = threadIdx.x;
  __shared__ unsigned long long key[SORTN];
  __shared__ float sx1[NN], sy1[NN], sx2[NN], sy2[NN], sar[NN], ssc[NN];
  __shared__ unsigned char sup[NN];
  __shared__ int sV, sMin;

  if (tid == 0) sV = 0;
  __syncthreads();
  int cntv = 0;
  const float* cf = conf + (size_t)b * NN;
  for (int i = tid; i < SORTN; i += 256) {
    unsigned long long k;
    if (i < NN) {
      float s = cf[i];
      unsigned rank = (unsigned)(NN - 1 - i);   // larger rank = smaller index -> wins desc ties
      if (s > 0.5f) { k = (((unsigned long long)__float_as_uint(s)) << 32) | rank; cntv++; }
      else k = (unsigned long long)rank;        // high32 = 0: sorts after all valid
    } else k = 0ull;
    key[i] = k;
  }
  atomicAdd(&sV, cntv);
  __syncthreads();
  const int V = sV;

  // bitonic sort, descending
  for (int kk = 2; kk <= SORTN; kk <<= 1) {
    for (int j = kk >> 1; j > 0; j >>= 1) {
      for (int i = tid; i < SORTN; i += 256) {
        int ixj = i ^ j;
        if (ixj > i) {
          unsigned long long a = key[i], c = key[ixj];
          bool dirDesc = ((i & kk) == 0);
          if ((a < c) == dirDesc) { key[i] = c; key[ixj] = a; }
        }
      }
      __syncthreads();
    }
  }

  // gather sorted valid boxes, clip to [0,1], areas
  const float* bbb = bbox + (size_t)b * NN * 4;
  for (int i = tid; i < V; i += 256) {
    unsigned long long k = key[i];
    int idx = NN - 1 - (int)(unsigned)(k & 0xFFFFFFFFull);
    float s = __uint_as_float((unsigned)(k >> 32));
    const float* bp = bbb + (size_t)idx * 4;
    float x1 = fminf(fmaxf(bp[0], 0.0f), 1.0f);
    float y1 = fminf(fmaxf(bp[1], 0.0f), 1.0f);
    float x2 = fminf(fmaxf(bp[2], 0.0f), 1.0f);
    float y2 = fminf(fmaxf(bp[3], 0.0f), 1.0f);
    sx1[i] = x1; sy1[i] = y1; sx2[i] = x2; sy2[i] = y2;
    sar[i] = (x2 - x1) * (y2 - y1);
    ssc[i] = s;
    sup[i] = 0;
  }
  __syncthreads();

  int kept = 0, cur = 0;
  float* ob = out + (size_t)b * 50 * 5;
  while (kept < 50 && cur < V) {
    int nxt = -1;
    for (int base = cur; base < V; base += 256) {
      if (tid == 0) sMin = 0x7FFFFFFF;
      __syncthreads();
      int i = base + tid;
      if (i < V && !sup[i]) atomicMin(&sMin, i);
      __syncthreads();
      if (sMin != 0x7FFFFFFF) { nxt = sMin; break; }
    }
    if (nxt < 0) break;
    float kx1 = sx1[nxt], ky1 = sy1[nxt], kx2 = sx2[nxt], ky2 = sy2[nxt], ka = sar[nxt];
    if (tid == 0) {
      float* r = ob + kept * 5;
      r[0] = kx1; r[1] = ky1; r[2] = kx2; r[3] = ky2; r[4] = ssc[nxt];
    }
    kept++;
    for (int jj = nxt + 1 + tid; jj < V; jj += 256) {
      if (!sup[jj]) {
        float xx1 = fmaxf(kx1, sx1[jj]);
        float yy1 = fmaxf(ky1, sy1[jj]);
        float xx2 = fminf(kx2, sx2[jj]);
        float yy2 = fminf(ky2, sy2[jj]);
        float inter = fmaxf(xx2 - xx1, 0.0f) * fmaxf(yy2 - yy1, 0.0f);
        float iou = inter / ((ka + sar[jj]) - inter);
        if (!(iou < 0.3f)) sup[jj] = 1;   // NaN -> suppressed, exactly like torch/jax
      }
    }
    cur = nxt + 1;
    __syncthreads();
  }
  // pad remaining rows: boxes 0, score -1
  for (int r = kept + tid; r < 50; r += 256) {
    float* q = ob + r * 5;
    q[0] = 0.0f; q[1] = 0.0f; q[2] = 0.0f; q[3] = 0.0f; q[4] = -1.0f;
  }
}

// ---------------- launch ----------------
extern "C" void kernel_launch(void* const* d_in, const int* in_sizes, int n_in,
                              void* d_out, int out_size, void* d_ws, size_t ws_size,
                              hipStream_t stream)
{
  const float* features = (const float*)d_in[0];
  const float* b1w = (const float*)d_in[1];  const float* b1b = (const float*)d_in[2];
  const float* bg1w = (const float*)d_in[3]; const float* bg1b = (const float*)d_in[4];
  const float* b2w = (const float*)d_in[5];  const float* b2b = (const float*)d_in[6];
  const float* bg2w = (const float*)d_in[7]; const float* bg2b = (const float*)d_in[8];
  const float* b3w = (const float*)d_in[9];  const float* b3b = (const float*)d_in[10];
  const float* bg3w = (const float*)d_in[11]; const float* bg3b = (const float*)d_in[12];
  const float* b4w = (const float*)d_in[13]; const float* b4b = (const float*)d_in[14];
  const float* c1w = (const float*)d_in[15]; const float* c1b = (const float*)d_in[16];
  const float* cg1w = (const float*)d_in[17]; const float* cg1b = (const float*)d_in[18];
  const float* c2w = (const float*)d_in[19]; const float* c2b = (const float*)d_in[20];
  const float* cg2w = (const float*)d_in[21]; const float* cg2b = (const float*)d_in[22];
  const float* c3w = (const float*)d_in[23]; const float* c3b = (const float*)d_in[24];

  float* ws = (float*)d_ws;
  float* wt1b = ws; ws += 1179648;
  float* wt1c = ws; ws += 1179648;
  float* wt2b = ws; ws += 294912;
  float* wt2c = ws; ws += 294912;
  float* wt3b = ws; ws += 147456;
  float* wt4b = ws; ws += 4608;
  float* wt3c = ws; ws += 1152;
  float* t1b = ws; ws += 1605632;
  float* t1c = ws; ws += 1605632;
  float* t2b = ws; ws += 802816;
  float* t2c = ws; ws += 802816;
  float* t3b = ws; ws += 802816;
  float* bbox = ws; ws += 225792;
  float* conf = ws; ws += 56448;

  wtrans_all<<<12119, 256, 0, stream>>>(b1w, c1w, b2w, c2w, b3w, b4w, c3w,
                                        wt1b, wt1c, wt2b, wt2c, wt3b, wt4b, wt3c);
  // conv1 both heads: Cin=512, Cout=256, 16 co-blocks/head
  conv3x3_gn<<<dim3(32, 32), 256, 0, stream>>>(features, features, wt1b, wt1c,
      b1b, c1b, bg1w, cg1w, bg1b, cg1b, t1b, t1c, 512, 256, 16);
  // conv2 both heads: Cin=256, Cout=128, 8 co-blocks/head
  conv3x3_gn<<<dim3(16, 32), 256, 0, stream>>>(t1b, t1c, wt2b, wt2c,
      b2b, c2b, bg2w, cg2w, bg2b, cg2b, t2b, t2c, 256, 128, 8);
  // conv3 bbox only: Cin=128, Cout=128
  conv3x3_gn<<<dim3(8, 32), 256, 0, stream>>>(t2b, t2b, wt3b, wt3b,
      b3b, b3b, bg3w, bg3w, bg3b, bg3b, t3b, t3b, 128, 128, 8);
  heads_1x1<<<32, 256, 0, stream>>>(t3b, t2c, wt4b, wt3c, b4b, c3b, bbox, conf);
  nms_kernel<<<32, 256, 0, stream>>>(bbox, conf, (float*)d_out);
}

// Round 2
// 1105.557 us; speedup vs baseline: 1.2382x; 1.2382x over previous
//
#include <hip/hip_runtime.h>
#include <hip/hip_bf16.h>
#include <math.h>

#define CHUNK 16
#define NN 1764
#define SORTN 2048

// ---------------- weight transpose:  W[co][ci][k] -> Wt[(ci*9+k)][co] ----------------
template<int Co, int CiK>
__device__ inline void seg_tr(const float* __restrict__ src, float* __restrict__ dst, int i) {
  int co = i / CiK; int cik = i - co * CiK;
  dst[cik * Co + co] = src[i];
}

__global__ void wtrans_all(
  const float* __restrict__ b1w, const float* __restrict__ c1w,
  const float* __restrict__ b2w, const float* __restrict__ c2w,
  const float* __restrict__ b3w, const float* __restrict__ b4w,
  const float* __restrict__ c3w,
  float* __restrict__ wt1b, float* __restrict__ wt1c,
  float* __restrict__ wt2b, float* __restrict__ wt2c,
  float* __restrict__ wt3b, float* __restrict__ wt4b, float* __restrict__ wt3c)
{
  int j = blockIdx.x * blockDim.x + threadIdx.x;
  if (j < 1179648) { seg_tr<256, 4608>(b1w, wt1b, j); return; } j -= 1179648;
  if (j < 1179648) { seg_tr<256, 4608>(c1w, wt1c, j); return; } j -= 1179648;
  if (j < 294912)  { seg_tr<128, 2304>(b2w, wt2b, j); return; } j -= 294912;
  if (j < 294912)  { seg_tr<128, 2304>(c2w, wt2c, j); return; } j -= 294912;
  if (j < 147456)  { seg_tr<128, 1152>(b3w, wt3b, j); return; } j -= 147456;
  if (j < 4608)    { seg_tr<36, 128>(b4w, wt4b, j); return; }  j -= 4608;
  if (j < 1152)    { seg_tr<9, 128>(c3w, wt3c, j); return; }
}

// ---------------- fused conv3x3 + bias + GELU + GroupNorm(8ch groups) ----------------
// Lane layout: col = tid&15 -> output channel (co0+col); r = tid>>4 -> pixel row (r<14).
// Weights arrive as per-lane VECTOR loads (deep vmcnt pipelining, no SGPR pressure).
// Inputs from 16x16 zero-halo LDS tile via ds_read_b128, double-buffered, 1 barrier/chunk.
__global__ __launch_bounds__(256, 4) void conv3x3_gn(
    const float* __restrict__ in0, const float* __restrict__ in1,
    const float* __restrict__ wt0, const float* __restrict__ wt1,
    const float* __restrict__ bs0, const float* __restrict__ bs1,
    const float* __restrict__ gw0, const float* __restrict__ gw1,
    const float* __restrict__ gb0, const float* __restrict__ gb1,
    float* __restrict__ out0, float* __restrict__ out1,
    int Cin, int Cout, int cobPerHead)
{
  const int tid = threadIdx.x;
  const int bx  = blockIdx.x;
  const int b   = blockIdx.y;
  const int head = bx / cobPerHead;
  const int cob  = bx - head * cobPerHead;
  const float* in  = head ? in1  : in0;
  const float* wt  = head ? wt1  : wt0;
  const float* bs  = head ? bs1  : bs0;
  const float* gw  = head ? gw1  : gw0;
  const float* gb  = head ? gb1  : gb0;
  float* out       = head ? out1 : out0;
  const int co0 = cob * 16;

  const int col = tid & 15;          // output channel offset
  const int r   = tid >> 4;          // pixel row, active r<14
  const int co  = co0 + col;
  const bool ract = r < 14;

  __shared__ float tile[2][CHUNK][16][16];   // zero-halo tiles, 32 KB
  __shared__ float redS[4][16], redQ[4][16];
  __shared__ float colS[16], colQ[16];
  __shared__ float stats[4];

  // zero everything once (halo cells stay 0 forever)
  {
    float* tz = &tile[0][0][0][0];
    for (int i = tid; i < 2 * CHUNK * 256; i += 256) tz[i] = 0.0f;
  }
  __syncthreads();

  const int p = tid;
  const bool pa = p < 196;
  const int prow = p / 14, pcol = p - prow * 14;
  const float* inb = in + (size_t)b * Cin * 196;
  const int nch = Cin / CHUNK;

  // stage chunk 0 interior
  if (pa) {
#pragma unroll
    for (int ci = 0; ci < CHUNK; ++ci)
      tile[0][ci][prow + 1][pcol + 1] = inb[ci * 196 + p];
  }
  __syncthreads();

  float acc[14];
  {
    float bias = bs[co];
#pragma unroll
    for (int j = 0; j < 14; ++j) acc[j] = bias;
  }

  const float* wcol = wt + co;

  for (int cb = 0; cb < nch; ++cb) {
    const int cur = cb & 1;
    const bool more = (cb + 1 < nch);
    float v[CHUNK];
    if (more && pa) {
#pragma unroll
      for (int ci = 0; ci < CHUNK; ++ci)
        v[ci] = inb[((cb + 1) * CHUNK + ci) * 196 + p];
    }
    if (ract) {
      const float* wb = wcol + (size_t)(cb * CHUNK * 9) * Cout;
      for (int ci = 0; ci < CHUNK; ++ci) {
        float wv[9];
#pragma unroll
        for (int k = 0; k < 9; ++k) wv[k] = wb[(size_t)(ci * 9 + k) * Cout];
        float nb[3][16];
#pragma unroll
        for (int dr = 0; dr < 3; ++dr) {
          const float4* rp = (const float4*)(&tile[cur][ci][r + dr][0]);
          float4 a = rp[0], bq = rp[1], cq = rp[2], dq = rp[3];
          nb[dr][0]  = a.x;  nb[dr][1]  = a.y;  nb[dr][2]  = a.z;  nb[dr][3]  = a.w;
          nb[dr][4]  = bq.x; nb[dr][5]  = bq.y; nb[dr][6]  = bq.z; nb[dr][7]  = bq.w;
          nb[dr][8]  = cq.x; nb[dr][9]  = cq.y; nb[dr][10] = cq.z; nb[dr][11] = cq.w;
          nb[dr][12] = dq.x; nb[dr][13] = dq.y; nb[dr][14] = dq.z; nb[dr][15] = dq.w;
        }
#pragma unroll
        for (int ky = 0; ky < 3; ++ky)
#pragma unroll
          for (int kx = 0; kx < 3; ++kx) {
            float w = wv[ky * 3 + kx];
#pragma unroll
            for (int j = 0; j < 14; ++j)
              acc[j] = fmaf(w, nb[ky][j + kx], acc[j]);
          }
      }
    }
    if (more && pa) {
#pragma unroll
      for (int ci = 0; ci < CHUNK; ++ci)
        tile[1 - cur][ci][prow + 1][pcol + 1] = v[ci];
    }
    __syncthreads();
  }

  // GELU (erf, exact) + per-group reduction
  float s = 0.0f, q = 0.0f;
  if (ract) {
#pragma unroll
    for (int j = 0; j < 14; ++j) {
      float vv = acc[j];
      float g = 0.5f * vv * (1.0f + erff(vv * 0.70710678118654752440f));
      acc[j] = g;
      s += g; q += g * g;
    }
  }
  // sum over the 4 rows within each wave (lane stride 16)
  s += __shfl_down(s, 32, 64); q += __shfl_down(q, 32, 64);
  s += __shfl_down(s, 16, 64); q += __shfl_down(q, 16, 64);
  const int wv_ = tid >> 6, lane = tid & 63;
  if (lane < 16) { redS[wv_][lane] = s; redQ[wv_][lane] = q; }
  __syncthreads();
  if (tid < 16) {
    colS[tid] = redS[0][tid] + redS[1][tid] + redS[2][tid] + redS[3][tid];
    colQ[tid] = redQ[0][tid] + redQ[1][tid] + redQ[2][tid] + redQ[3][tid];
  }
  __syncthreads();
  if (tid < 2) {
    float S = 0.0f, Q = 0.0f;
#pragma unroll
    for (int c = 0; c < 8; ++c) { S += colS[tid * 8 + c]; Q += colQ[tid * 8 + c]; }
    float m  = S * (1.0f / 1568.0f);
    float va = Q * (1.0f / 1568.0f) - m * m;
    stats[tid * 2]     = m;
    stats[tid * 2 + 1] = 1.0f / sqrtf(va + 1e-5f);
  }
  __syncthreads();
  if (ract) {
    const int g2 = (col >> 3) * 2;
    float m = stats[g2], iv = stats[g2 + 1];
    float gwv = gw[co] * iv;
    float gbv = fmaf(-m, gwv, gb[co]);
    float* op = out + ((size_t)b * Cout + co) * 196 + r * 14;
#pragma unroll
    for (int j = 0; j < 14; ++j) op[j] = fmaf(acc[j], gwv, gbv);
  }
}

// ---------------- 1x1 heads: bbox (128->36) and cls (128->9, sigmoid) ----------------
__global__ __launch_bounds__(256) void heads_1x1(
    const float* __restrict__ tb, const float* __restrict__ tc,
    const float* __restrict__ wtb, const float* __restrict__ wtc, // [128][36], [128][9]
    const float* __restrict__ bb,  const float* __restrict__ bc,
    float* __restrict__ bbox, float* __restrict__ conf)
{
  const int b = blockIdx.x, tid = threadIdx.x;
  if (tid >= 196) return;
  const int p = tid;
  float ab[36], ac[9];
#pragma unroll
  for (int o = 0; o < 36; ++o) ab[o] = bb[o];
#pragma unroll
  for (int o = 0; o < 9; ++o) ac[o] = bc[o];
  const float* pb = tb + (size_t)b * 128 * 196 + p;
  const float* pc = tc + (size_t)b * 128 * 196 + p;
  for (int ci = 0; ci < 128; ++ci) {
    float xb = pb[ci * 196];
    float xc = pc[ci * 196];
    const float* wb = wtb + ci * 36;
    const float* wc = wtc + ci * 9;
#pragma unroll
    for (int o = 0; o < 36; ++o) ab[o] = fmaf(wb[o], xb, ab[o]);
#pragma unroll
    for (int o = 0; o < 9; ++o)  ac[o] = fmaf(wc[o], xc, ac[o]);
  }
  const size_t nb = (size_t)b * NN;
#pragma unroll
  for (int a = 0; a < 9; ++a) {
    size_t n = nb + (size_t)p * 9 + a;
#pragma unroll
    for (int d = 0; d < 4; ++d) bbox[n * 4 + d] = ab[a * 4 + d];
    conf[n] = 1.0f / (1.0f + expf(-ac[a]));
  }
}

// ---------------- per-image greedy NMS with early exit at 50 kept ----------------
__global__ __launch_bounds__(256) void nms_kernel(
  const float* __restrict__ bbox, const float* __restrict__ conf, float* __restrict__ out)
{
  const int b = blockIdx.x, tid = threadIdx.x;
  __shared__ unsigned long long key[SORTN];
  __shared__ float sx1[NN], sy1[NN], sx2[NN], sy2[NN], sar[NN], ssc[NN];
  __shared__ unsigned char sup[NN];
  __shared__ int sV, sMin;

  if (tid == 0) sV = 0;
  __syncthreads();
  int cntv = 0;
  const float* cf = conf + (size_t)b * NN;
  for (int i = tid; i < SORTN; i += 256) {
    unsigned long long k;
    if (i < NN) {
      float s = cf[i];
      unsigned rank = (unsigned)(NN - 1 - i);
      if (s > 0.5f) { k = (((unsigned long long)__float_as_uint(s)) << 32) | rank; cntv++; }
      else k = (unsigned long long)rank;
    } else k = 0ull;
    key[i] = k;
  }
  atomicAdd(&sV, cntv);
  __syncthreads();
  const int V = sV;

  for (int kk = 2; kk <= SORTN; kk <<= 1) {
    for (int j = kk >> 1; j > 0; j >>= 1) {
      for (int i = tid; i < SORTN; i += 256) {
        int ixj = i ^ j;
        if (ixj > i) {
          unsigned long long a = key[i], c = key[ixj];
          bool dirDesc = ((i & kk) == 0);
          if ((a < c) == dirDesc) { key[i] = c; key[ixj] = a; }
        }
      }
      __syncthreads();
    }
  }

  const float* bbb = bbox + (size_t)b * NN * 4;
  for (int i = tid; i < V; i += 256) {
    unsigned long long k = key[i];
    int idx = NN - 1 - (int)(unsigned)(k & 0xFFFFFFFFull);
    float s = __uint_as_float((unsigned)(k >> 32));
    const float* bp = bbb + (size_t)idx * 4;
    float x1 = fminf(fmaxf(bp[0], 0.0f), 1.0f);
    float y1 = fminf(fmaxf(bp[1], 0.0f), 1.0f);
    float x2 = fminf(fmaxf(bp[2], 0.0f), 1.0f);
    float y2 = fminf(fmaxf(bp[3], 0.0f), 1.0f);
    sx1[i] = x1; sy1[i] = y1; sx2[i] = x2; sy2[i] = y2;
    sar[i] = (x2 - x1) * (y2 - y1);
    ssc[i] = s;
    sup[i] = 0;
  }
  __syncthreads();

  int kept = 0, cur = 0;
  float* ob = out + (size_t)b * 50 * 5;
  while (kept < 50 && cur < V) {
    int nxt = -1;
    for (int base = cur; base < V; base += 256) {
      if (tid == 0) sMin = 0x7FFFFFFF;
      __syncthreads();
      int i = base + tid;
      if (i < V && !sup[i]) atomicMin(&sMin, i);
      __syncthreads();
      if (sMin != 0x7FFFFFFF) { nxt = sMin; break; }
    }
    if (nxt < 0) break;
    float kx1 = sx1[nxt], ky1 = sy1[nxt], kx2 = sx2[nxt], ky2 = sy2[nxt], ka = sar[nxt];
    if (tid == 0) {
      float* rr = ob + kept * 5;
      rr[0] = kx1; rr[1] = ky1; rr[2] = kx2; rr[3] = ky2; rr[4] = ssc[nxt];
    }
    kept++;
    for (int jj = nxt + 1 + tid; jj < V; jj += 256) {
      if (!sup[jj]) {
        float xx1 = fmaxf(kx1, sx1[jj]);
        float yy1 = fmaxf(ky1, sy1[jj]);
        float xx2 = fminf(kx2, sx2[jj]);
        float yy2 = fminf(ky2, sy2[jj]);
        float inter = fmaxf(xx2 - xx1, 0.0f) * fmaxf(yy2 - yy1, 0.0f);
        float iou = inter / ((ka + sar[jj]) - inter);
        if (!(iou < 0.3f)) sup[jj] = 1;
      }
    }
    cur = nxt + 1;
    __syncthreads();
  }
  for (int rr = kept + tid; rr < 50; rr += 256) {
    float* qq = ob + rr * 5;
    qq[0] = 0.0f; qq[1] = 0.0f; qq[2] = 0.0f; qq[3] = 0.0f; qq[4] = -1.0f;
  }
}

// ---------------- launch ----------------
extern "C" void kernel_launch(void* const* d_in, const int* in_sizes, int n_in,
                              void* d_out, int out_size, void* d_ws, size_t ws_size,
                              hipStream_t stream)
{
  const float* features = (const float*)d_in[0];
  const float* b1w = (const float*)d_in[1];  const float* b1b = (const float*)d_in[2];
  const float* bg1w = (const float*)d_in[3]; const float* bg1b = (const float*)d_in[4];
  const float* b2w = (const float*)d_in[5];  const float* b2b = (const float*)d_in[6];
  const float* bg2w = (const float*)d_in[7]; const float* bg2b = (const float*)d_in[8];
  const float* b3w = (const float*)d_in[9];  const float* b3b = (const float*)d_in[10];
  const float* bg3w = (const float*)d_in[11]; const float* bg3b = (const float*)d_in[12];
  const float* b4w = (const float*)d_in[13]; const float* b4b = (const float*)d_in[14];
  const float* c1w = (const float*)d_in[15]; const float* c1b = (const float*)d_in[16];
  const float* cg1w = (const float*)d_in[17]; const float* cg1b = (const float*)d_in[18];
  const float* c2w = (const float*)d_in[19]; const float* c2b = (const float*)d_in[20];
  const float* cg2w = (const float*)d_in[21]; const float* cg2b = (const float*)d_in[22];
  const float* c3w = (const float*)d_in[23]; const float* c3b = (const float*)d_in[24];

  float* ws = (float*)d_ws;
  float* wt1b = ws; ws += 1179648;
  float* wt1c = ws; ws += 1179648;
  float* wt2b = ws; ws += 294912;
  float* wt2c = ws; ws += 294912;
  float* wt3b = ws; ws += 147456;
  float* wt4b = ws; ws += 4608;
  float* wt3c = ws; ws += 1152;
  float* t1b = ws; ws += 1605632;
  float* t1c = ws; ws += 1605632;
  float* t2b = ws; ws += 802816;
  float* t2c = ws; ws += 802816;
  float* t3b = ws; ws += 802816;
  float* bbox = ws; ws += 225792;
  float* conf = ws; ws += 56448;

  wtrans_all<<<12119, 256, 0, stream>>>(b1w, c1w, b2w, c2w, b3w, b4w, c3w,
                                        wt1b, wt1c, wt2b, wt2c, wt3b, wt4b, wt3c);
  conv3x3_gn<<<dim3(32, 32), 256, 0, stream>>>(features, features, wt1b, wt1c,
      b1b, c1b, bg1w, cg1w, bg1b, cg1b, t1b, t1c, 512, 256, 16);
  conv3x3_gn<<<dim3(16, 32), 256, 0, stream>>>(t1b, t1c, wt2b, wt2c,
      b2b, c2b, bg2w, cg2w, bg2b, cg2b, t2b, t2c, 256, 128, 8);
  conv3x3_gn<<<dim3(8, 32), 256, 0, stream>>>(t2b, t2b, wt3b, wt3b,
      b3b, b3b, bg3w, bg3w, bg3b, bg3b, t3b, t3b, 128, 128, 8);
  heads_1x1<<<32, 256, 0, stream>>>(t3b, t2c, wt4b, wt3c, b4b, c3b, bbox, conf);
  nms_kernel<<<32, 256, 0, stream>>>(bbox, conf, (float*)d_out);
}

// Round 3
// 1009.506 us; speedup vs baseline: 1.3560x; 1.0951x over previous
//
#include <hip/hip_runtime.h>
#include <hip/hip_bf16.h>
#include <math.h>

#define CHUNK 16
#define NN 1764
#define SORTN 2048

// ---------------- weight packing ----------------
// 3x3 convs:  W[co][ci][3][3] -> Wp[ci][co][12]  (9 taps + 3 pad, dwordx4-friendly)
template<int Co, int Ci>
__device__ inline void seg_pack(const float* __restrict__ src, float* __restrict__ dst, int i) {
  int co = i / (Ci * 9); int rem = i - co * (Ci * 9); int ci = rem / 9; int k = rem - ci * 9;
  dst[((size_t)ci * Co + co) * 12 + k] = src[i];
}
// 1x1 convs:  W[co][ci] -> Wt[ci][co]
template<int Co, int CiK>
__device__ inline void seg_tr(const float* __restrict__ src, float* __restrict__ dst, int i) {
  int co = i / CiK; int cik = i - co * CiK;
  dst[cik * Co + co] = src[i];
}

__global__ void wtrans_all(
  const float* __restrict__ b1w, const float* __restrict__ c1w,
  const float* __restrict__ b2w, const float* __restrict__ c2w,
  const float* __restrict__ b3w, const float* __restrict__ b4w,
  const float* __restrict__ c3w,
  float* __restrict__ wp1b, float* __restrict__ wp1c,
  float* __restrict__ wp2b, float* __restrict__ wp2c,
  float* __restrict__ wp3b, float* __restrict__ wt4b, float* __restrict__ wt3c)
{
  int j = blockIdx.x * blockDim.x + threadIdx.x;
  if (j < 1179648) { seg_pack<256, 512>(b1w, wp1b, j); return; } j -= 1179648;
  if (j < 1179648) { seg_pack<256, 512>(c1w, wp1c, j); return; } j -= 1179648;
  if (j < 294912)  { seg_pack<128, 256>(b2w, wp2b, j); return; } j -= 294912;
  if (j < 294912)  { seg_pack<128, 256>(c2w, wp2c, j); return; } j -= 294912;
  if (j < 147456)  { seg_pack<128, 128>(b3w, wp3b, j); return; } j -= 147456;
  if (j < 4608)    { seg_tr<36, 128>(b4w, wt4b, j); return; }  j -= 4608;
  if (j < 1152)    { seg_tr<9, 128>(c3w, wt3c, j); return; }
}

// ---------------- fused conv3x3 + bias + GELU + GroupNorm(8ch groups) ----------------
// Lane layout: col = tid&15; r = tid>>4 (pixel row, active r<14).
// COPT output channels per thread (co0+col, co0+col+16, ...): FMA per LDS byte scales
// with COPT. Weights packed [ci][co][12] -> 3 dwordx4 per co from one base.
template<int COPT>
__global__ __launch_bounds__(256, 2) void conv3x3_gn(
    const float* __restrict__ in0, const float* __restrict__ in1,
    const float* __restrict__ wt0, const float* __restrict__ wt1,
    const float* __restrict__ bs0, const float* __restrict__ bs1,
    const float* __restrict__ gw0, const float* __restrict__ gw1,
    const float* __restrict__ gb0, const float* __restrict__ gb1,
    float* __restrict__ out0, float* __restrict__ out1,
    int Cin, int Cout, int cobPerHead)
{
  const int tid = threadIdx.x;
  const int bx  = blockIdx.x;
  const int b   = blockIdx.y;
  const int head = bx / cobPerHead;
  const int cob  = bx - head * cobPerHead;
  const float* in  = head ? in1  : in0;
  const float* wt  = head ? wt1  : wt0;
  const float* bs  = head ? bs1  : bs0;
  const float* gw  = head ? gw1  : gw0;
  const float* gb  = head ? gb1  : gb0;
  float* out       = head ? out1 : out0;
  const int co0 = cob * (16 * COPT);

  const int col = tid & 15;
  const int r   = tid >> 4;
  const int co  = co0 + col;          // first of COPT channels (stride 16)
  const bool ract = r < 14;

  __shared__ float tile[2][CHUNK][16][16];          // zero-halo tiles, 32 KB
  __shared__ float redS[4][16 * COPT], redQ[4][16 * COPT];
  __shared__ float colS[16 * COPT], colQ[16 * COPT];
  __shared__ float stats[4 * COPT];

  {
    float* tz = &tile[0][0][0][0];
    for (int i = tid; i < 2 * CHUNK * 256; i += 256) tz[i] = 0.0f;
  }
  __syncthreads();

  const int p = tid;
  const bool pa = p < 196;
  const int prow = p / 14, pcol = p - prow * 14;
  const float* inb = in + (size_t)b * Cin * 196;
  const int nch = Cin / CHUNK;

  if (pa) {
#pragma unroll
    for (int ci = 0; ci < CHUNK; ++ci)
      tile[0][ci][prow + 1][pcol + 1] = inb[ci * 196 + p];
  }
  __syncthreads();

  float acc[COPT][14];
#pragma unroll
  for (int c = 0; c < COPT; ++c) {
    float bias = bs[co + c * 16];
#pragma unroll
    for (int j = 0; j < 14; ++j) acc[c][j] = bias;
  }

  for (int cb = 0; cb < nch; ++cb) {
    const int cur = cb & 1;
    const bool more = (cb + 1 < nch);
    float v[CHUNK];
    if (more && pa) {
#pragma unroll
      for (int ci = 0; ci < CHUNK; ++ci)
        v[ci] = inb[((cb + 1) * CHUNK + ci) * 196 + p];
    }
    if (ract) {
      for (int ci = 0; ci < CHUNK; ++ci) {
        // weights: 3 dwordx4 per co, second co at +768B immediate
        const float4* wq = (const float4*)(wt + ((size_t)(cb * CHUNK + ci) * Cout + co) * 12);
        float wv[COPT][12];
#pragma unroll
        for (int c = 0; c < COPT; ++c) {
          float4 w0 = wq[c * 48 + 0], w1 = wq[c * 48 + 1], w2 = wq[c * 48 + 2];
          wv[c][0] = w0.x; wv[c][1] = w0.y; wv[c][2]  = w0.z; wv[c][3]  = w0.w;
          wv[c][4] = w1.x; wv[c][5] = w1.y; wv[c][6]  = w1.z; wv[c][7]  = w1.w;
          wv[c][8] = w2.x; wv[c][9] = w2.y; wv[c][10] = w2.z; wv[c][11] = w2.w;
        }
        float nb[3][16];
#pragma unroll
        for (int dr = 0; dr < 3; ++dr) {
          const float4* rp = (const float4*)(&tile[cur][ci][r + dr][0]);
          float4 a = rp[0], bq = rp[1], cq = rp[2], dq = rp[3];
          nb[dr][0]  = a.x;  nb[dr][1]  = a.y;  nb[dr][2]  = a.z;  nb[dr][3]  = a.w;
          nb[dr][4]  = bq.x; nb[dr][5]  = bq.y; nb[dr][6]  = bq.z; nb[dr][7]  = bq.w;
          nb[dr][8]  = cq.x; nb[dr][9]  = cq.y; nb[dr][10] = cq.z; nb[dr][11] = cq.w;
          nb[dr][12] = dq.x; nb[dr][13] = dq.y; nb[dr][14] = dq.z; nb[dr][15] = dq.w;
        }
#pragma unroll
        for (int ky = 0; ky < 3; ++ky)
#pragma unroll
          for (int kx = 0; kx < 3; ++kx) {
#pragma unroll
            for (int c = 0; c < COPT; ++c) {
              float w = wv[c][ky * 3 + kx];
#pragma unroll
              for (int j = 0; j < 14; ++j)
                acc[c][j] = fmaf(w, nb[ky][j + kx], acc[c][j]);
            }
          }
      }
    }
    if (more && pa) {
#pragma unroll
      for (int ci = 0; ci < CHUNK; ++ci)
        tile[1 - cur][ci][prow + 1][pcol + 1] = v[ci];
    }
    __syncthreads();
  }

  // GELU (erf, exact) + per-group reduction (groups of 8 consecutive channels)
  float s[COPT], q[COPT];
#pragma unroll
  for (int c = 0; c < COPT; ++c) { s[c] = 0.0f; q[c] = 0.0f; }
  if (ract) {
#pragma unroll
    for (int c = 0; c < COPT; ++c)
#pragma unroll
      for (int j = 0; j < 14; ++j) {
        float vv = acc[c][j];
        float g = 0.5f * vv * (1.0f + erff(vv * 0.70710678118654752440f));
        acc[c][j] = g;
        s[c] += g; q[c] += g * g;
      }
  }
#pragma unroll
  for (int c = 0; c < COPT; ++c) {
    s[c] += __shfl_down(s[c], 32, 64); q[c] += __shfl_down(q[c], 32, 64);
    s[c] += __shfl_down(s[c], 16, 64); q[c] += __shfl_down(q[c], 16, 64);
  }
  const int wv_ = tid >> 6, lane = tid & 63;
  if (lane < 16) {
#pragma unroll
    for (int c = 0; c < COPT; ++c) {
      redS[wv_][c * 16 + lane] = s[c];
      redQ[wv_][c * 16 + lane] = q[c];
    }
  }
  __syncthreads();
  if (tid < 16 * COPT) {
    colS[tid] = redS[0][tid] + redS[1][tid] + redS[2][tid] + redS[3][tid];
    colQ[tid] = redQ[0][tid] + redQ[1][tid] + redQ[2][tid] + redQ[3][tid];
  }
  __syncthreads();
  if (tid < 2 * COPT) {
    float S = 0.0f, Q = 0.0f;
#pragma unroll
    for (int c = 0; c < 8; ++c) { S += colS[tid * 8 + c]; Q += colQ[tid * 8 + c]; }
    float m  = S * (1.0f / 1568.0f);
    float va = Q * (1.0f / 1568.0f) - m * m;
    stats[tid * 2]     = m;
    stats[tid * 2 + 1] = 1.0f / sqrtf(va + 1e-5f);
  }
  __syncthreads();
  if (ract) {
#pragma unroll
    for (int c = 0; c < COPT; ++c) {
      const int oc = c * 16 + col;           // channel offset within block
      const int g2 = (oc >> 3) * 2;
      float m = stats[g2], iv = stats[g2 + 1];
      float gwv = gw[co0 + oc] * iv;
      float gbv = fmaf(-m, gwv, gb[co0 + oc]);
      float* op = out + ((size_t)b * Cout + co0 + oc) * 196 + r * 14;
#pragma unroll
      for (int j = 0; j < 14; ++j) op[j] = fmaf(acc[c][j], gwv, gbv);
    }
  }
}

// ---------------- 1x1 heads: bbox (128->36) and cls (128->9, sigmoid) ----------------
__global__ __launch_bounds__(256) void heads_1x1(
    const float* __restrict__ tb, const float* __restrict__ tc,
    const float* __restrict__ wtb, const float* __restrict__ wtc, // [128][36], [128][9]
    const float* __restrict__ bb,  const float* __restrict__ bc,
    float* __restrict__ bbox, float* __restrict__ conf)
{
  const int b = blockIdx.x, tid = threadIdx.x;
  if (tid >= 196) return;
  const int p = tid;
  float ab[36], ac[9];
#pragma unroll
  for (int o = 0; o < 36; ++o) ab[o] = bb[o];
#pragma unroll
  for (int o = 0; o < 9; ++o) ac[o] = bc[o];
  const float* pb = tb + (size_t)b * 128 * 196 + p;
  const float* pc = tc + (size_t)b * 128 * 196 + p;
  for (int ci = 0; ci < 128; ++ci) {
    float xb = pb[ci * 196];
    float xc = pc[ci * 196];
    const float* wb = wtb + ci * 36;
    const float* wc = wtc + ci * 9;
#pragma unroll
    for (int o = 0; o < 36; ++o) ab[o] = fmaf(wb[o], xb, ab[o]);
#pragma unroll
    for (int o = 0; o < 9; ++o)  ac[o] = fmaf(wc[o], xc, ac[o]);
  }
  const size_t nb = (size_t)b * NN;
#pragma unroll
  for (int a = 0; a < 9; ++a) {
    size_t n = nb + (size_t)p * 9 + a;
#pragma unroll
    for (int d = 0; d < 4; ++d) bbox[n * 4 + d] = ab[a * 4 + d];
    conf[n] = 1.0f / (1.0f + expf(-ac[a]));
  }
}

// ---------------- per-image greedy NMS with early exit at 50 kept ----------------
__global__ __launch_bounds__(256) void nms_kernel(
  const float* __restrict__ bbox, const float* __restrict__ conf, float* __restrict__ out)
{
  const int b = blockIdx.x, tid = threadIdx.x;
  __shared__ unsigned long long key[SORTN];
  __shared__ float sx1[NN], sy1[NN], sx2[NN], sy2[NN], sar[NN], ssc[NN];
  __shared__ unsigned char sup[NN];
  __shared__ int sV, sMin;

  if (tid == 0) sV = 0;
  __syncthreads();
  int cntv = 0;
  const float* cf = conf + (size_t)b * NN;
  for (int i = tid; i < SORTN; i += 256) {
    unsigned long long k;
    if (i < NN) {
      float s = cf[i];
      unsigned rank = (unsigned)(NN - 1 - i);
      if (s > 0.5f) { k = (((unsigned long long)__float_as_uint(s)) << 32) | rank; cntv++; }
      else k = (unsigned long long)rank;
    } else k = 0ull;
    key[i] = k;
  }
  atomicAdd(&sV, cntv);
  __syncthreads();
  const int V = sV;

  for (int kk = 2; kk <= SORTN; kk <<= 1) {
    for (int j = kk >> 1; j > 0; j >>= 1) {
      for (int i = tid; i < SORTN; i += 256) {
        int ixj = i ^ j;
        if (ixj > i) {
          unsigned long long a = key[i], c = key[ixj];
          bool dirDesc = ((i & kk) == 0);
          if ((a < c) == dirDesc) { key[i] = c; key[ixj] = a; }
        }
      }
      __syncthreads();
    }
  }

  const float* bbb = bbox + (size_t)b * NN * 4;
  for (int i = tid; i < V; i += 256) {
    unsigned long long k = key[i];
    int idx = NN - 1 - (int)(unsigned)(k & 0xFFFFFFFFull);
    float s = __uint_as_float((unsigned)(k >> 32));
    const float* bp = bbb + (size_t)idx * 4;
    float x1 = fminf(fmaxf(bp[0], 0.0f), 1.0f);
    float y1 = fminf(fmaxf(bp[1], 0.0f), 1.0f);
    float x2 = fminf(fmaxf(bp[2], 0.0f), 1.0f);
    float y2 = fminf(fmaxf(bp[3], 0.0f), 1.0f);
    sx1[i] = x1; sy1[i] = y1; sx2[i] = x2; sy2[i] = y2;
    sar[i] = (x2 - x1) * (y2 - y1);
    ssc[i] = s;
    sup[i] = 0;
  }
  __syncthreads();

  int kept = 0, cur = 0;
  float* ob = out + (size_t)b * 50 * 5;
  while (kept < 50 && cur < V) {
    int nxt = -1;
    for (int base = cur; base < V; base += 256) {
      if (tid == 0) sMin = 0x7FFFFFFF;
      __syncthreads();
      int i = base + tid;
      if (i < V && !sup[i]) atomicMin(&sMin, i);
      __syncthreads();
      if (sMin != 0x7FFFFFFF) { nxt = sMin; break; }
    }
    if (nxt < 0) break;
    float kx1 = sx1[nxt], ky1 = sy1[nxt], kx2 = sx2[nxt], ky2 = sy2[nxt], ka = sar[nxt];
    if (tid == 0) {
      float* rr = ob + kept * 5;
      rr[0] = kx1; rr[1] = ky1; rr[2] = kx2; rr[3] = ky2; rr[4] = ssc[nxt];
    }
    kept++;
    for (int jj = nxt + 1 + tid; jj < V; jj += 256) {
      if (!sup[jj]) {
        float xx1 = fmaxf(kx1, sx1[jj]);
        float yy1 = fmaxf(ky1, sy1[jj]);
        float xx2 = fminf(kx2, sx2[jj]);
        float yy2 = fminf(ky2, sy2[jj]);
        float inter = fmaxf(xx2 - xx1, 0.0f) * fmaxf(yy2 - yy1, 0.0f);
        float iou = inter / ((ka + sar[jj]) - inter);
        if (!(iou < 0.3f)) sup[jj] = 1;
      }
    }
    cur = nxt + 1;
    __syncthreads();
  }
  for (int rr = kept + tid; rr < 50; rr += 256) {
    float* qq = ob + rr * 5;
    qq[0] = 0.0f; qq[1] = 0.0f; qq[2] = 0.0f; qq[3] = 0.0f; qq[4] = -1.0f;
  }
}

// ---------------- launch ----------------
extern "C" void kernel_launch(void* const* d_in, const int* in_sizes, int n_in,
                              void* d_out, int out_size, void* d_ws, size_t ws_size,
                              hipStream_t stream)
{
  const float* features = (const float*)d_in[0];
  const float* b1w = (const float*)d_in[1];  const float* b1b = (const float*)d_in[2];
  const float* bg1w = (const float*)d_in[3]; const float* bg1b = (const float*)d_in[4];
  const float* b2w = (const float*)d_in[5];  const float* b2b = (const float*)d_in[6];
  const float* bg2w = (const float*)d_in[7]; const float* bg2b = (const float*)d_in[8];
  const float* b3w = (const float*)d_in[9];  const float* b3b = (const float*)d_in[10];
  const float* bg3w = (const float*)d_in[11]; const float* bg3b = (const float*)d_in[12];
  const float* b4w = (const float*)d_in[13]; const float* b4b = (const float*)d_in[14];
  const float* c1w = (const float*)d_in[15]; const float* c1b = (const float*)d_in[16];
  const float* cg1w = (const float*)d_in[17]; const float* cg1b = (const float*)d_in[18];
  const float* c2w = (const float*)d_in[19]; const float* c2b = (const float*)d_in[20];
  const float* cg2w = (const float*)d_in[21]; const float* cg2b = (const float*)d_in[22];
  const float* c3w = (const float*)d_in[23]; const float* c3b = (const float*)d_in[24];

  float* ws = (float*)d_ws;
  float* wp1b = ws; ws += 1572864;   // 512*256*12
  float* wp1c = ws; ws += 1572864;
  float* wp2b = ws; ws += 393216;    // 256*128*12
  float* wp2c = ws; ws += 393216;
  float* wp3b = ws; ws += 196608;    // 128*128*12
  float* wt4b = ws; ws += 4608;
  float* wt3c = ws; ws += 1152;
  float* t1b = ws; ws += 1605632;
  float* t1c = ws; ws += 1605632;
  float* t2b = ws; ws += 802816;
  float* t2c = ws; ws += 802816;
  float* t3b = ws; ws += 802816;
  float* bbox = ws; ws += 225792;
  float* conf = ws; ws += 56448;

  wtrans_all<<<12119, 256, 0, stream>>>(b1w, c1w, b2w, c2w, b3w, b4w, c3w,
                                        wp1b, wp1c, wp2b, wp2c, wp3b, wt4b, wt3c);
  // conv1 both heads: Cin=512, Cout=256, COPT=2 (32 co/block), 8 co-blocks/head
  conv3x3_gn<2><<<dim3(16, 32), 256, 0, stream>>>(features, features, wp1b, wp1c,
      b1b, c1b, bg1w, cg1w, bg1b, cg1b, t1b, t1c, 512, 256, 8);
  // conv2 both heads: Cin=256, Cout=128, COPT=1 (16 co/block), 8 co-blocks/head
  conv3x3_gn<1><<<dim3(16, 32), 256, 0, stream>>>(t1b, t1c, wp2b, wp2c,
      b2b, c2b, bg2w, cg2w, bg2b, cg2b, t2b, t2c, 256, 128, 8);
  // conv3 bbox only: Cin=128, Cout=128, COPT=1
  conv3x3_gn<1><<<dim3(8, 32), 256, 0, stream>>>(t2b, t2b, wp3b, wp3b,
      b3b, b3b, bg3w, bg3w, bg3b, bg3b, t3b, t3b, 128, 128, 8);
  heads_1x1<<<32, 256, 0, stream>>>(t3b, t2c, wt4b, wt3c, b4b, c3b, bbox, conf);
  nms_kernel<<<32, 256, 0, stream>>>(bbox, conf, (float*)d_out);
}

// Round 4
// 944.508 us; speedup vs baseline: 1.4493x; 1.0688x over previous
//
#include <hip/hip_runtime.h>
#include <hip/hip_bf16.h>
#include <math.h>

#define CHUNK 16
#define NN 1764
#define SORTN 2048

// ---------------- weight packing ----------------
// 3x3 convs:  W[co][ci][3][3] -> Wp[ci][co][12]  (9 taps + 3 pad, dwordx4-friendly)
template<int Co, int Ci>
__device__ inline void seg_pack(const float* __restrict__ src, float* __restrict__ dst, int i) {
  int co = i / (Ci * 9); int rem = i - co * (Ci * 9); int ci = rem / 9; int k = rem - ci * 9;
  dst[((size_t)ci * Co + co) * 12 + k] = src[i];
}
// 1x1 convs:  W[co][ci] -> Wt[ci][co]
template<int Co, int CiK>
__device__ inline void seg_tr(const float* __restrict__ src, float* __restrict__ dst, int i) {
  int co = i / CiK; int cik = i - co * CiK;
  dst[cik * Co + co] = src[i];
}

__global__ void wtrans_all(
  const float* __restrict__ b1w, const float* __restrict__ c1w,
  const float* __restrict__ b2w, const float* __restrict__ c2w,
  const float* __restrict__ b3w, const float* __restrict__ b4w,
  const float* __restrict__ c3w,
  float* __restrict__ wp1b, float* __restrict__ wp1c,
  float* __restrict__ wp2b, float* __restrict__ wp2c,
  float* __restrict__ wp3b, float* __restrict__ wt4b, float* __restrict__ wt3c)
{
  int j = blockIdx.x * blockDim.x + threadIdx.x;
  if (j < 1179648) { seg_pack<256, 512>(b1w, wp1b, j); return; } j -= 1179648;
  if (j < 1179648) { seg_pack<256, 512>(c1w, wp1c, j); return; } j -= 1179648;
  if (j < 294912)  { seg_pack<128, 256>(b2w, wp2b, j); return; } j -= 294912;
  if (j < 294912)  { seg_pack<128, 256>(c2w, wp2c, j); return; } j -= 294912;
  if (j < 147456)  { seg_pack<128, 128>(b3w, wp3b, j); return; } j -= 147456;
  if (j < 4608)    { seg_tr<36, 128>(b4w, wt4b, j); return; }  j -= 4608;
  if (j < 1152)    { seg_tr<9, 128>(c3w, wt3c, j); return; }
}

// ---------------- split-K partial conv3x3 (no bias/GELU/GN) ----------------
// Lane layout: col = tid&15; r = tid>>4 (pixel row, active r<14).
// blockIdx.z = K-split index s; block covers Cin range [s*cinPerSplit, (s+1)*cinPerSplit).
// Partial sums -> po[s][b][co][196]. grid z-fold restores 4 blocks/CU occupancy.
template<int COPT>
__global__ __launch_bounds__(256, 4) void conv3x3_part(
    const float* __restrict__ in0, const float* __restrict__ in1,
    const float* __restrict__ wt0, const float* __restrict__ wt1,
    float* __restrict__ po0, float* __restrict__ po1,
    int Cin, int Cout, int cobPerHead, int cinPerSplit, size_t sStride)
{
  const int tid = threadIdx.x;
  const int bx  = blockIdx.x;
  const int b   = blockIdx.y;
  const int s   = blockIdx.z;
  const int head = bx / cobPerHead;
  const int cob  = bx - head * cobPerHead;
  const float* in  = head ? in1  : in0;
  const float* wt  = head ? wt1  : wt0;
  float* po        = head ? po1  : po0;
  const int co0 = cob * (16 * COPT);

  const int col = tid & 15;
  const int r   = tid >> 4;
  const int co  = co0 + col;
  const bool ract = r < 14;

  __shared__ float tile[2][CHUNK][16][16];   // zero-halo tiles, 32 KB

  {
    float* tz = &tile[0][0][0][0];
    for (int i = tid; i < 2 * CHUNK * 256; i += 256) tz[i] = 0.0f;
  }
  __syncthreads();

  const int p = tid;
  const bool pa = p < 196;
  const int prow = p / 14, pcol = p - prow * 14;
  const float* inb = in + (size_t)b * Cin * 196;
  const int cb0 = (s * cinPerSplit) / CHUNK;
  const int nch = cinPerSplit / CHUNK;

  if (pa) {
#pragma unroll
    for (int ci = 0; ci < CHUNK; ++ci)
      tile[0][ci][prow + 1][pcol + 1] = inb[(cb0 * CHUNK + ci) * 196 + p];
  }
  __syncthreads();

  float acc[COPT][14];
#pragma unroll
  for (int c = 0; c < COPT; ++c)
#pragma unroll
    for (int j = 0; j < 14; ++j) acc[c][j] = 0.0f;

  for (int lcb = 0; lcb < nch; ++lcb) {
    const int cbg = cb0 + lcb;
    const int cur = lcb & 1;
    const bool more = (lcb + 1 < nch);
    float v[CHUNK];
    if (more && pa) {
#pragma unroll
      for (int ci = 0; ci < CHUNK; ++ci)
        v[ci] = inb[((cbg + 1) * CHUNK + ci) * 196 + p];
    }
    if (ract) {
      for (int ci = 0; ci < CHUNK; ++ci) {
        const float4* wq = (const float4*)(wt + ((size_t)(cbg * CHUNK + ci) * Cout + co) * 12);
        float wv[COPT][12];
#pragma unroll
        for (int c = 0; c < COPT; ++c) {
          float4 w0 = wq[c * 48 + 0], w1 = wq[c * 48 + 1], w2 = wq[c * 48 + 2];
          wv[c][0] = w0.x; wv[c][1] = w0.y; wv[c][2]  = w0.z; wv[c][3]  = w0.w;
          wv[c][4] = w1.x; wv[c][5] = w1.y; wv[c][6]  = w1.z; wv[c][7]  = w1.w;
          wv[c][8] = w2.x; wv[c][9] = w2.y; wv[c][10] = w2.z; wv[c][11] = w2.w;
        }
        float nb[3][16];
#pragma unroll
        for (int dr = 0; dr < 3; ++dr) {
          const float4* rp = (const float4*)(&tile[cur][ci][r + dr][0]);
          float4 a = rp[0], bq = rp[1], cq = rp[2], dq = rp[3];
          nb[dr][0]  = a.x;  nb[dr][1]  = a.y;  nb[dr][2]  = a.z;  nb[dr][3]  = a.w;
          nb[dr][4]  = bq.x; nb[dr][5]  = bq.y; nb[dr][6]  = bq.z; nb[dr][7]  = bq.w;
          nb[dr][8]  = cq.x; nb[dr][9]  = cq.y; nb[dr][10] = cq.z; nb[dr][11] = cq.w;
          nb[dr][12] = dq.x; nb[dr][13] = dq.y; nb[dr][14] = dq.z; nb[dr][15] = dq.w;
        }
#pragma unroll
        for (int ky = 0; ky < 3; ++ky)
#pragma unroll
          for (int kx = 0; kx < 3; ++kx) {
#pragma unroll
            for (int c = 0; c < COPT; ++c) {
              float w = wv[c][ky * 3 + kx];
#pragma unroll
              for (int j = 0; j < 14; ++j)
                acc[c][j] = fmaf(w, nb[ky][j + kx], acc[c][j]);
            }
          }
      }
    }
    if (more && pa) {
#pragma unroll
      for (int ci = 0; ci < CHUNK; ++ci)
        tile[1 - cur][ci][prow + 1][pcol + 1] = v[ci];
    }
    __syncthreads();
  }

  if (ract) {
#pragma unroll
    for (int c = 0; c < COPT; ++c) {
      const int oc = c * 16 + col;
      float* op = po + (size_t)s * sStride + ((size_t)b * Cout + co0 + oc) * 196 + r * 14;
#pragma unroll
      for (int j = 0; j < 14; ++j) op[j] = acc[c][j];
    }
  }
}

// ---------------- combine partials + bias + GELU + GroupNorm(8ch groups) ----------------
// block: (head*cobPerHead+cob, batch); thread = pixel (196 active).
template<int S>
__global__ __launch_bounds__(256) void combine_gn(
    const float* __restrict__ po0, const float* __restrict__ po1,
    const float* __restrict__ bs0, const float* __restrict__ bs1,
    const float* __restrict__ gw0, const float* __restrict__ gw1,
    const float* __restrict__ gb0, const float* __restrict__ gb1,
    float* __restrict__ out0, float* __restrict__ out1,
    int Cout, int cobPerHead, size_t sStride)
{
  const int tid = threadIdx.x, bx = blockIdx.x, b = blockIdx.y;
  const int head = bx / cobPerHead, cob = bx - head * cobPerHead;
  const float* po = head ? po1 : po0;
  const float* bs = head ? bs1 : bs0;
  const float* gw = head ? gw1 : gw0;
  const float* gb = head ? gb1 : gb0;
  float* out      = head ? out1 : out0;
  const int co0 = cob * 16;

  __shared__ float red[4][4];
  __shared__ float stats[4];

  const int p = tid;
  const bool pa = p < 196;
  float v[16];
  float s0 = 0.f, q0 = 0.f, s1 = 0.f, q1 = 0.f;
  if (pa) {
#pragma unroll
    for (int c = 0; c < 16; ++c) {
      const size_t base = ((size_t)b * Cout + co0 + c) * 196 + p;
      float x = bs[co0 + c];
#pragma unroll
      for (int s = 0; s < S; ++s) x += po[base + (size_t)s * sStride];
      float g = 0.5f * x * (1.0f + erff(x * 0.70710678118654752440f));
      v[c] = g;
      if (c < 8) { s0 += g; q0 += g * g; } else { s1 += g; q1 += g * g; }
    }
  }
#pragma unroll
  for (int off = 32; off > 0; off >>= 1) {
    s0 += __shfl_down(s0, off, 64); q0 += __shfl_down(q0, off, 64);
    s1 += __shfl_down(s1, off, 64); q1 += __shfl_down(q1, off, 64);
  }
  const int wave = tid >> 6, lane = tid & 63;
  if (lane == 0) { red[wave][0] = s0; red[wave][1] = q0; red[wave][2] = s1; red[wave][3] = q1; }
  __syncthreads();
  if (tid == 0) {
    float S0 = red[0][0] + red[1][0] + red[2][0] + red[3][0];
    float Q0 = red[0][1] + red[1][1] + red[2][1] + red[3][1];
    float S1 = red[0][2] + red[1][2] + red[2][2] + red[3][2];
    float Q1 = red[0][3] + red[1][3] + red[2][3] + red[3][3];
    float m0 = S0 * (1.0f / 1568.0f);
    float v0 = Q0 * (1.0f / 1568.0f) - m0 * m0;
    float m1 = S1 * (1.0f / 1568.0f);
    float v1 = Q1 * (1.0f / 1568.0f) - m1 * m1;
    stats[0] = m0; stats[1] = 1.0f / sqrtf(v0 + 1e-5f);
    stats[2] = m1; stats[3] = 1.0f / sqrtf(v1 + 1e-5f);
  }
  __syncthreads();
  if (pa) {
    float m0 = stats[0], i0 = stats[1], m1 = stats[2], i1 = stats[3];
#pragma unroll
    for (int c = 0; c < 16; ++c) {
      float m  = (c < 8) ? m0 : m1;
      float iv = (c < 8) ? i0 : i1;
      float y = (v[c] - m) * iv * gw[co0 + c] + gb[co0 + c];
      out[((size_t)b * Cout + co0 + c) * 196 + p] = y;
    }
  }
}

// ---------------- 1x1 heads: bbox (128->36) and cls (128->9, sigmoid) ----------------
__global__ __launch_bounds__(256) void heads_1x1(
    const float* __restrict__ tb, const float* __restrict__ tc,
    const float* __restrict__ wtb, const float* __restrict__ wtc, // [128][36], [128][9]
    const float* __restrict__ bb,  const float* __restrict__ bc,
    float* __restrict__ bbox, float* __restrict__ conf)
{
  const int b = blockIdx.x, tid = threadIdx.x;
  if (tid >= 196) return;
  const int p = tid;
  float ab[36], ac[9];
#pragma unroll
  for (int o = 0; o < 36; ++o) ab[o] = bb[o];
#pragma unroll
  for (int o = 0; o < 9; ++o) ac[o] = bc[o];
  const float* pb = tb + (size_t)b * 128 * 196 + p;
  const float* pc = tc + (size_t)b * 128 * 196 + p;
  for (int ci = 0; ci < 128; ++ci) {
    float xb = pb[ci * 196];
    float xc = pc[ci * 196];
    const float* wb = wtb + ci * 36;
    const float* wc = wtc + ci * 9;
#pragma unroll
    for (int o = 0; o < 36; ++o) ab[o] = fmaf(wb[o], xb, ab[o]);
#pragma unroll
    for (int o = 0; o < 9; ++o)  ac[o] = fmaf(wc[o], xc, ac[o]);
  }
  const size_t nb = (size_t)b * NN;
#pragma unroll
  for (int a = 0; a < 9; ++a) {
    size_t n = nb + (size_t)p * 9 + a;
#pragma unroll
    for (int d = 0; d < 4; ++d) bbox[n * 4 + d] = ab[a * 4 + d];
    conf[n] = 1.0f / (1.0f + expf(-ac[a]));
  }
}

// ---------------- per-image greedy NMS with early exit at 50 kept ----------------
__global__ __launch_bounds__(256) void nms_kernel(
  const float* __restrict__ bbox, const float* __restrict__ conf, float* __restrict__ out)
{
  const int b = blockIdx.x, tid = threadIdx.x;
  __shared__ unsigned long long key[SORTN];
  __shared__ float sx1[NN], sy1[NN], sx2[NN], sy2[NN], sar[NN], ssc[NN];
  __shared__ unsigned char sup[NN];
  __shared__ int sV, sMin;

  if (tid == 0) sV = 0;
  __syncthreads();
  int cntv = 0;
  const float* cf = conf + (size_t)b * NN;
  for (int i = tid; i < SORTN; i += 256) {
    unsigned long long k;
    if (i < NN) {
      float s = cf[i];
      unsigned rank = (unsigned)(NN - 1 - i);
      if (s > 0.5f) { k = (((unsigned long long)__float_as_uint(s)) << 32) | rank; cntv++; }
      else k = (unsigned long long)rank;
    } else k = 0ull;
    key[i] = k;
  }
  atomicAdd(&sV, cntv);
  __syncthreads();
  const int V = sV;

  for (int kk = 2; kk <= SORTN; kk <<= 1) {
    for (int j = kk >> 1; j > 0; j >>= 1) {
      for (int i = tid; i < SORTN; i += 256) {
        int ixj = i ^ j;
        if (ixj > i) {
          unsigned long long a = key[i], c = key[ixj];
          bool dirDesc = ((i & kk) == 0);
          if ((a < c) == dirDesc) { key[i] = c; key[ixj] = a; }
        }
      }
      __syncthreads();
    }
  }

  const float* bbb = bbox + (size_t)b * NN * 4;
  for (int i = tid; i < V; i += 256) {
    unsigned long long k = key[i];
    int idx = NN - 1 - (int)(unsigned)(k & 0xFFFFFFFFull);
    float s = __uint_as_float((unsigned)(k >> 32));
    const float* bp = bbb + (size_t)idx * 4;
    float x1 = fminf(fmaxf(bp[0], 0.0f), 1.0f);
    float y1 = fminf(fmaxf(bp[1], 0.0f), 1.0f);
    float x2 = fminf(fmaxf(bp[2], 0.0f), 1.0f);
    float y2 = fminf(fmaxf(bp[3], 0.0f), 1.0f);
    sx1[i] = x1; sy1[i] = y1; sx2[i] = x2; sy2[i] = y2;
    sar[i] = (x2 - x1) * (y2 - y1);
    ssc[i] = s;
    sup[i] = 0;
  }
  __syncthreads();

  int kept = 0, cur = 0;
  float* ob = out + (size_t)b * 50 * 5;
  while (kept < 50 && cur < V) {
    int nxt = -1;
    for (int base = cur; base < V; base += 256) {
      if (tid == 0) sMin = 0x7FFFFFFF;
      __syncthreads();
      int i = base + tid;
      if (i < V && !sup[i]) atomicMin(&sMin, i);
      __syncthreads();
      if (sMin != 0x7FFFFFFF) { nxt = sMin; break; }
    }
    if (nxt < 0) break;
    float kx1 = sx1[nxt], ky1 = sy1[nxt], kx2 = sx2[nxt], ky2 = sy2[nxt], ka = sar[nxt];
    if (tid == 0) {
      float* rr = ob + kept * 5;
      rr[0] = kx1; rr[1] = ky1; rr[2] = kx2; rr[3] = ky2; rr[4] = ssc[nxt];
    }
    kept++;
    for (int jj = nxt + 1 + tid; jj < V; jj += 256) {
      if (!sup[jj]) {
        float xx1 = fmaxf(kx1, sx1[jj]);
        float yy1 = fmaxf(ky1, sy1[jj]);
        float xx2 = fminf(kx2, sx2[jj]);
        float yy2 = fminf(ky2, sy2[jj]);
        float inter = fmaxf(xx2 - xx1, 0.0f) * fmaxf(yy2 - yy1, 0.0f);
        float iou = inter / ((ka + sar[jj]) - inter);
        if (!(iou < 0.3f)) sup[jj] = 1;
      }
    }
    cur = nxt + 1;
    __syncthreads();
  }
  for (int rr = kept + tid; rr < 50; rr += 256) {
    float* qq = ob + rr * 5;
    qq[0] = 0.0f; qq[1] = 0.0f; qq[2] = 0.0f; qq[3] = 0.0f; qq[4] = -1.0f;
  }
}

// ---------------- launch ----------------
extern "C" void kernel_launch(void* const* d_in, const int* in_sizes, int n_in,
                              void* d_out, int out_size, void* d_ws, size_t ws_size,
                              hipStream_t stream)
{
  const float* features = (const float*)d_in[0];
  const float* b1w = (const float*)d_in[1];  const float* b1b = (const float*)d_in[2];
  const float* bg1w = (const float*)d_in[3]; const float* bg1b = (const float*)d_in[4];
  const float* b2w = (const float*)d_in[5];  const float* b2b = (const float*)d_in[6];
  const float* bg2w = (const float*)d_in[7]; const float* bg2b = (const float*)d_in[8];
  const float* b3w = (const float*)d_in[9];  const float* b3b = (const float*)d_in[10];
  const float* bg3w = (const float*)d_in[11]; const float* bg3b = (const float*)d_in[12];
  const float* b4w = (const float*)d_in[13]; const float* b4b = (const float*)d_in[14];
  const float* c1w = (const float*)d_in[15]; const float* c1b = (const float*)d_in[16];
  const float* cg1w = (const float*)d_in[17]; const float* cg1b = (const float*)d_in[18];
  const float* c2w = (const float*)d_in[19]; const float* c2b = (const float*)d_in[20];
  const float* cg2w = (const float*)d_in[21]; const float* cg2b = (const float*)d_in[22];
  const float* c3w = (const float*)d_in[23]; const float* c3b = (const float*)d_in[24];

  float* ws = (float*)d_ws;
  float* wp1b = ws; ws += 1572864;   // 512*256*12
  float* wp1c = ws; ws += 1572864;
  float* wp2b = ws; ws += 393216;    // 256*128*12
  float* wp2c = ws; ws += 393216;
  float* wp3b = ws; ws += 196608;    // 128*128*12
  float* wt4b = ws; ws += 4608;
  float* wt3c = ws; ws += 1152;
  float* t1b = ws; ws += 1605632;
  float* t1c = ws; ws += 1605632;
  float* t2b = ws; ws += 802816;
  float* t2c = ws; ws += 802816;
  float* t3b = ws; ws += 802816;
  float* P   = ws; ws += 6422528;    // partial region (aliased across layers)
  float* bbox = ws; ws += 225792;
  float* conf = ws; ws += 56448;

  wtrans_all<<<12119, 256, 0, stream>>>(b1w, c1w, b2w, c2w, b3w, b4w, c3w,
                                        wp1b, wp1c, wp2b, wp2c, wp3b, wt4b, wt3c);

  // conv1: Cin=512, Cout=256, COPT=2, split-K S=2 -> 1024 blocks (4/CU)
  {
    const size_t sStr = (size_t)32 * 256 * 196;          // 1605632
    conv3x3_part<2><<<dim3(16, 32, 2), 256, 0, stream>>>(
        features, features, wp1b, wp1c, P, P + 2 * sStr, 512, 256, 8, 256, sStr);
    combine_gn<2><<<dim3(32, 32), 256, 0, stream>>>(
        P, P + 2 * sStr, b1b, c1b, bg1w, cg1w, bg1b, cg1b, t1b, t1c, 256, 16, sStr);
  }
  // conv2: Cin=256, Cout=128, COPT=1, S=2 -> 1024 blocks
  {
    const size_t sStr = (size_t)32 * 128 * 196;          // 802816
    conv3x3_part<1><<<dim3(16, 32, 2), 256, 0, stream>>>(
        t1b, t1c, wp2b, wp2c, P, P + 2 * sStr, 256, 128, 8, 128, sStr);
    combine_gn<2><<<dim3(16, 32), 256, 0, stream>>>(
        P, P + 2 * sStr, b2b, c2b, bg2w, cg2w, bg2b, cg2b, t2b, t2c, 128, 8, sStr);
  }
  // conv3 (bbox only): Cin=128, Cout=128, COPT=1, S=4 -> 1024 blocks
  {
    const size_t sStr = (size_t)32 * 128 * 196;
    conv3x3_part<1><<<dim3(8, 32, 4), 256, 0, stream>>>(
        t2b, t2b, wp3b, wp3b, P, P, 128, 128, 8, 32, sStr);
    combine_gn<4><<<dim3(8, 32), 256, 0, stream>>>(
        P, P, b3b, b3b, bg3w, bg3w, bg3b, bg3b, t3b, t3b, 128, 8, sStr);
  }

  heads_1x1<<<32, 256, 0, stream>>>(t3b, t2c, wt4b, wt3c, b4b, c3b, bbox, conf);
  nms_kernel<<<32, 256, 0, stream>>>(bbox, conf, (float*)d_out);
}

// Round 5
// 894.578 us; speedup vs baseline: 1.5302x; 1.0558x over previous
//
#include <hip/hip_runtime.h>
#include <hip/hip_bf16.h>
#include <math.h>

#define CHUNK 16
#define NN 1764
#define SORTN 2048

// ---------------- weight packing ----------------
// 3x3 convs:  W[co][ci][3][3] -> Wp[ci][co][12]  (9 taps + 3 pad, dwordx4-friendly)
template<int Co, int Ci>
__device__ inline void seg_pack(const float* __restrict__ src, float* __restrict__ dst, int i) {
  int co = i / (Ci * 9); int rem = i - co * (Ci * 9); int ci = rem / 9; int k = rem - ci * 9;
  dst[((size_t)ci * Co + co) * 12 + k] = src[i];
}
// 1x1 convs:  W[co][ci] -> Wt[ci][co]
template<int Co, int CiK>
__device__ inline void seg_tr(const float* __restrict__ src, float* __restrict__ dst, int i) {
  int co = i / CiK; int cik = i - co * CiK;
  dst[cik * Co + co] = src[i];
}

__global__ void wtrans_all(
  const float* __restrict__ b1w, const float* __restrict__ c1w,
  const float* __restrict__ b2w, const float* __restrict__ c2w,
  const float* __restrict__ b3w, const float* __restrict__ b4w,
  const float* __restrict__ c3w,
  float* __restrict__ wp1b, float* __restrict__ wp1c,
  float* __restrict__ wp2b, float* __restrict__ wp2c,
  float* __restrict__ wp3b, float* __restrict__ wt4b, float* __restrict__ wt3c)
{
  int j = blockIdx.x * blockDim.x + threadIdx.x;
  if (j < 1179648) { seg_pack<256, 512>(b1w, wp1b, j); return; } j -= 1179648;
  if (j < 1179648) { seg_pack<256, 512>(c1w, wp1c, j); return; } j -= 1179648;
  if (j < 294912)  { seg_pack<128, 256>(b2w, wp2b, j); return; } j -= 294912;
  if (j < 294912)  { seg_pack<128, 256>(c2w, wp2c, j); return; } j -= 294912;
  if (j < 147456)  { seg_pack<128, 128>(b3w, wp3b, j); return; } j -= 147456;
  if (j < 4608)    { seg_tr<36, 128>(b4w, wt4b, j); return; }  j -= 4608;
  if (j < 1152)    { seg_tr<9, 128>(c3w, wt3c, j); return; }
}

// ---------------- split-K partial conv3x3 (no bias/GELU/GN) ----------------
// Lane layout: col = tid&15; r = tid>>4 (pixel row, active r<14).
// COPT=4: nb rows (12 ds_read_b128/ci) reused across 4 output channels ->
// 1008 FMA-cycles per 12 LDS insts per wave: LDS pipe ~50% of FMA issue.
// blockIdx.z = K-split; 2 blocks/CU resident (launch_bounds 256,2), grids sized 512.
template<int COPT>
__global__ __launch_bounds__(256, 2) void conv3x3_part(
    const float* __restrict__ in0, const float* __restrict__ in1,
    const float* __restrict__ wt0, const float* __restrict__ wt1,
    float* __restrict__ po0, float* __restrict__ po1,
    int Cin, int Cout, int cobPerHead, int cinPerSplit, size_t sStride)
{
  const int tid = threadIdx.x;
  const int bx  = blockIdx.x;
  const int b   = blockIdx.y;
  const int s   = blockIdx.z;
  const int head = bx / cobPerHead;
  const int cob  = bx - head * cobPerHead;
  const float* in  = head ? in1  : in0;
  const float* wt  = head ? wt1  : wt0;
  float* po        = head ? po1  : po0;
  const int co0 = cob * (16 * COPT);

  const int col = tid & 15;
  const int r   = tid >> 4;
  const int co  = co0 + col;
  const bool ract = r < 14;

  __shared__ float tile[2][CHUNK][16][16];   // zero-halo tiles, 32 KB

  {
    float* tz = &tile[0][0][0][0];
    for (int i = tid; i < 2 * CHUNK * 256; i += 256) tz[i] = 0.0f;
  }
  __syncthreads();

  const int p = tid;
  const bool pa = p < 196;
  const int prow = p / 14, pcol = p - prow * 14;
  const float* inb = in + (size_t)b * Cin * 196;
  const int cb0 = (s * cinPerSplit) / CHUNK;
  const int nch = cinPerSplit / CHUNK;

  if (pa) {
#pragma unroll
    for (int ci = 0; ci < CHUNK; ++ci)
      tile[0][ci][prow + 1][pcol + 1] = inb[(cb0 * CHUNK + ci) * 196 + p];
  }
  __syncthreads();

  float acc[COPT][14];
#pragma unroll
  for (int c = 0; c < COPT; ++c)
#pragma unroll
    for (int j = 0; j < 14; ++j) acc[c][j] = 0.0f;

  for (int lcb = 0; lcb < nch; ++lcb) {
    const int cbg = cb0 + lcb;
    const int cur = lcb & 1;
    const bool more = (lcb + 1 < nch);
    float v[CHUNK];
    if (more && pa) {
#pragma unroll
      for (int ci = 0; ci < CHUNK; ++ci)
        v[ci] = inb[((cbg + 1) * CHUNK + ci) * 196 + p];
    }
    if (ract) {
      for (int ci = 0; ci < CHUNK; ++ci) {
        const float4* wq = (const float4*)(wt + ((size_t)(cbg * CHUNK + ci) * Cout + co) * 12);
        float wv[COPT][12];
#pragma unroll
        for (int c = 0; c < COPT; ++c) {
          float4 w0 = wq[c * 48 + 0], w1 = wq[c * 48 + 1], w2 = wq[c * 48 + 2];
          wv[c][0] = w0.x; wv[c][1] = w0.y; wv[c][2]  = w0.z; wv[c][3]  = w0.w;
          wv[c][4] = w1.x; wv[c][5] = w1.y; wv[c][6]  = w1.z; wv[c][7]  = w1.w;
          wv[c][8] = w2.x; wv[c][9] = w2.y; wv[c][10] = w2.z; wv[c][11] = w2.w;
        }
        float nb[3][16];
#pragma unroll
        for (int dr = 0; dr < 3; ++dr) {
          const float4* rp = (const float4*)(&tile[cur][ci][r + dr][0]);
          float4 a = rp[0], bq = rp[1], cq = rp[2], dq = rp[3];
          nb[dr][0]  = a.x;  nb[dr][1]  = a.y;  nb[dr][2]  = a.z;  nb[dr][3]  = a.w;
          nb[dr][4]  = bq.x; nb[dr][5]  = bq.y; nb[dr][6]  = bq.z; nb[dr][7]  = bq.w;
          nb[dr][8]  = cq.x; nb[dr][9]  = cq.y; nb[dr][10] = cq.z; nb[dr][11] = cq.w;
          nb[dr][12] = dq.x; nb[dr][13] = dq.y; nb[dr][14] = dq.z; nb[dr][15] = dq.w;
        }
#pragma unroll
        for (int ky = 0; ky < 3; ++ky)
#pragma unroll
          for (int kx = 0; kx < 3; ++kx) {
#pragma unroll
            for (int c = 0; c < COPT; ++c) {
              float w = wv[c][ky * 3 + kx];
#pragma unroll
              for (int j = 0; j < 14; ++j)
                acc[c][j] = fmaf(w, nb[ky][j + kx], acc[c][j]);
            }
          }
      }
    }
    if (more && pa) {
#pragma unroll
      for (int ci = 0; ci < CHUNK; ++ci)
        tile[1 - cur][ci][prow + 1][pcol + 1] = v[ci];
    }
    __syncthreads();
  }

  if (ract) {
#pragma unroll
    for (int c = 0; c < COPT; ++c) {
      const int oc = c * 16 + col;
      float* op = po + (size_t)s * sStride + ((size_t)b * Cout + co0 + oc) * 196 + r * 14;
#pragma unroll
      for (int j = 0; j < 14; ++j) op[j] = acc[c][j];
    }
  }
}

// ---------------- combine partials + bias + GELU + GroupNorm(8ch groups) ----------------
// block: (head*cobPerHead+cob, batch); thread = pixel (196 active); 16 channels/block.
template<int S>
__global__ __launch_bounds__(256) void combine_gn(
    const float* __restrict__ po0, const float* __restrict__ po1,
    const float* __restrict__ bs0, const float* __restrict__ bs1,
    const float* __restrict__ gw0, const float* __restrict__ gw1,
    const float* __restrict__ gb0, const float* __restrict__ gb1,
    float* __restrict__ out0, float* __restrict__ out1,
    int Cout, int cobPerHead, size_t sStride)
{
  const int tid = threadIdx.x, bx = blockIdx.x, b = blockIdx.y;
  const int head = bx / cobPerHead, cob = bx - head * cobPerHead;
  const float* po = head ? po1 : po0;
  const float* bs = head ? bs1 : bs0;
  const float* gw = head ? gw1 : gw0;
  const float* gb = head ? gb1 : gb0;
  float* out      = head ? out1 : out0;
  const int co0 = cob * 16;

  __shared__ float red[4][4];
  __shared__ float stats[4];

  const int p = tid;
  const bool pa = p < 196;
  float v[16];
  float s0 = 0.f, q0 = 0.f, s1 = 0.f, q1 = 0.f;
  if (pa) {
#pragma unroll
    for (int c = 0; c < 16; ++c) {
      const size_t base = ((size_t)b * Cout + co0 + c) * 196 + p;
      float x = bs[co0 + c];
#pragma unroll
      for (int s = 0; s < S; ++s) x += po[base + (size_t)s * sStride];
      float g = 0.5f * x * (1.0f + erff(x * 0.70710678118654752440f));
      v[c] = g;
      if (c < 8) { s0 += g; q0 += g * g; } else { s1 += g; q1 += g * g; }
    }
  }
#pragma unroll
  for (int off = 32; off > 0; off >>= 1) {
    s0 += __shfl_down(s0, off, 64); q0 += __shfl_down(q0, off, 64);
    s1 += __shfl_down(s1, off, 64); q1 += __shfl_down(q1, off, 64);
  }
  const int wave = tid >> 6, lane = tid & 63;
  if (lane == 0) { red[wave][0] = s0; red[wave][1] = q0; red[wave][2] = s1; red[wave][3] = q1; }
  __syncthreads();
  if (tid == 0) {
    float S0 = red[0][0] + red[1][0] + red[2][0] + red[3][0];
    float Q0 = red[0][1] + red[1][1] + red[2][1] + red[3][1];
    float S1 = red[0][2] + red[1][2] + red[2][2] + red[3][2];
    float Q1 = red[0][3] + red[1][3] + red[2][3] + red[3][3];
    float m0 = S0 * (1.0f / 1568.0f);
    float v0 = Q0 * (1.0f / 1568.0f) - m0 * m0;
    float m1 = S1 * (1.0f / 1568.0f);
    float v1 = Q1 * (1.0f / 1568.0f) - m1 * m1;
    stats[0] = m0; stats[1] = 1.0f / sqrtf(v0 + 1e-5f);
    stats[2] = m1; stats[3] = 1.0f / sqrtf(v1 + 1e-5f);
  }
  __syncthreads();
  if (pa) {
    float m0 = stats[0], i0 = stats[1], m1 = stats[2], i1 = stats[3];
#pragma unroll
    for (int c = 0; c < 16; ++c) {
      float m  = (c < 8) ? m0 : m1;
      float iv = (c < 8) ? i0 : i1;
      float y = (v[c] - m) * iv * gw[co0 + c] + gb[co0 + c];
      out[((size_t)b * Cout + co0 + c) * 196 + p] = y;
    }
  }
}

// ---------------- 1x1 heads: bbox (128->36) and cls (128->9, sigmoid) ----------------
__global__ __launch_bounds__(256) void heads_1x1(
    const float* __restrict__ tb, const float* __restrict__ tc,
    const float* __restrict__ wtb, const float* __restrict__ wtc, // [128][36], [128][9]
    const float* __restrict__ bb,  const float* __restrict__ bc,
    float* __restrict__ bbox, float* __restrict__ conf)
{
  const int b = blockIdx.x, tid = threadIdx.x;
  if (tid >= 196) return;
  const int p = tid;
  float ab[36], ac[9];
#pragma unroll
  for (int o = 0; o < 36; ++o) ab[o] = bb[o];
#pragma unroll
  for (int o = 0; o < 9; ++o) ac[o] = bc[o];
  const float* pb = tb + (size_t)b * 128 * 196 + p;
  const float* pc = tc + (size_t)b * 128 * 196 + p;
  for (int ci = 0; ci < 128; ++ci) {
    float xb = pb[ci * 196];
    float xc = pc[ci * 196];
    const float* wb = wtb + ci * 36;
    const float* wc = wtc + ci * 9;
#pragma unroll
    for (int o = 0; o < 36; ++o) ab[o] = fmaf(wb[o], xb, ab[o]);
#pragma unroll
    for (int o = 0; o < 9; ++o)  ac[o] = fmaf(wc[o], xc, ac[o]);
  }
  const size_t nb = (size_t)b * NN;
#pragma unroll
  for (int a = 0; a < 9; ++a) {
    size_t n = nb + (size_t)p * 9 + a;
#pragma unroll
    for (int d = 0; d < 4; ++d) bbox[n * 4 + d] = ab[a * 4 + d];
    conf[n] = 1.0f / (1.0f + expf(-ac[a]));
  }
}

// ---------------- per-image greedy NMS with early exit at 50 kept ----------------
__global__ __launch_bounds__(256) void nms_kernel(
  const float* __restrict__ bbox, const float* __restrict__ conf, float* __restrict__ out)
{
  const int b = blockIdx.x, tid = threadIdx.x;
  __shared__ unsigned long long key[SORTN];
  __shared__ float sx1[NN], sy1[NN], sx2[NN], sy2[NN], sar[NN], ssc[NN];
  __shared__ unsigned char sup[NN];
  __shared__ int sV, sMin;

  if (tid == 0) sV = 0;
  __syncthreads();
  int cntv = 0;
  const float* cf = conf + (size_t)b * NN;
  for (int i = tid; i < SORTN; i += 256) {
    unsigned long long k;
    if (i < NN) {
      float s = cf[i];
      unsigned rank = (unsigned)(NN - 1 - i);
      if (s > 0.5f) { k = (((unsigned long long)__float_as_uint(s)) << 32) | rank; cntv++; }
      else k = (unsigned long long)rank;
    } else k = 0ull;
    key[i] = k;
  }
  atomicAdd(&sV, cntv);
  __syncthreads();
  const int V = sV;

  for (int kk = 2; kk <= SORTN; kk <<= 1) {
    for (int j = kk >> 1; j > 0; j >>= 1) {
      for (int i = tid; i < SORTN; i += 256) {
        int ixj = i ^ j;
        if (ixj > i) {
          unsigned long long a = key[i], c = key[ixj];
          bool dirDesc = ((i & kk) == 0);
          if ((a < c) == dirDesc) { key[i] = c; key[ixj] = a; }
        }
      }
      __syncthreads();
    }
  }

  const float* bbb = bbox + (size_t)b * NN * 4;
  for (int i = tid; i < V; i += 256) {
    unsigned long long k = key[i];
    int idx = NN - 1 - (int)(unsigned)(k & 0xFFFFFFFFull);
    float s = __uint_as_float((unsigned)(k >> 32));
    const float* bp = bbb + (size_t)idx * 4;
    float x1 = fminf(fmaxf(bp[0], 0.0f), 1.0f);
    float y1 = fminf(fmaxf(bp[1], 0.0f), 1.0f);
    float x2 = fminf(fmaxf(bp[2], 0.0f), 1.0f);
    float y2 = fminf(fmaxf(bp[3], 0.0f), 1.0f);
    sx1[i] = x1; sy1[i] = y1; sx2[i] = x2; sy2[i] = y2;
    sar[i] = (x2 - x1) * (y2 - y1);
    ssc[i] = s;
    sup[i] = 0;
  }
  __syncthreads();

  int kept = 0, cur = 0;
  float* ob = out + (size_t)b * 50 * 5;
  while (kept < 50 && cur < V) {
    int nxt = -1;
    for (int base = cur; base < V; base += 256) {
      if (tid == 0) sMin = 0x7FFFFFFF;
      __syncthreads();
      int i = base + tid;
      if (i < V && !sup[i]) atomicMin(&sMin, i);
      __syncthreads();
      if (sMin != 0x7FFFFFFF) { nxt = sMin; break; }
    }
    if (nxt < 0) break;
    float kx1 = sx1[nxt], ky1 = sy1[nxt], kx2 = sx2[nxt], ky2 = sy2[nxt], ka = sar[nxt];
    if (tid == 0) {
      float* rr = ob + kept * 5;
      rr[0] = kx1; rr[1] = ky1; rr[2] = kx2; rr[3] = ky2; rr[4] = ssc[nxt];
    }
    kept++;
    for (int jj = nxt + 1 + tid; jj < V; jj += 256) {
      if (!sup[jj]) {
        float xx1 = fmaxf(kx1, sx1[jj]);
        float yy1 = fmaxf(ky1, sy1[jj]);
        float xx2 = fminf(kx2, sx2[jj]);
        float yy2 = fminf(ky2, sy2[jj]);
        float inter = fmaxf(xx2 - xx1, 0.0f) * fmaxf(yy2 - yy1, 0.0f);
        float iou = inter / ((ka + sar[jj]) - inter);
        if (!(iou < 0.3f)) sup[jj] = 1;
      }
    }
    cur = nxt + 1;
    __syncthreads();
  }
  for (int rr = kept + tid; rr < 50; rr += 256) {
    float* qq = ob + rr * 5;
    qq[0] = 0.0f; qq[1] = 0.0f; qq[2] = 0.0f; qq[3] = 0.0f; qq[4] = -1.0f;
  }
}

// ---------------- launch ----------------
extern "C" void kernel_launch(void* const* d_in, const int* in_sizes, int n_in,
                              void* d_out, int out_size, void* d_ws, size_t ws_size,
                              hipStream_t stream)
{
  const float* features = (const float*)d_in[0];
  const float* b1w = (const float*)d_in[1];  const float* b1b = (const float*)d_in[2];
  const float* bg1w = (const float*)d_in[3]; const float* bg1b = (const float*)d_in[4];
  const float* b2w = (const float*)d_in[5];  const float* b2b = (const float*)d_in[6];
  const float* bg2w = (const float*)d_in[7]; const float* bg2b = (const float*)d_in[8];
  const float* b3w = (const float*)d_in[9];  const float* b3b = (const float*)d_in[10];
  const float* bg3w = (const float*)d_in[11]; const float* bg3b = (const float*)d_in[12];
  const float* b4w = (const float*)d_in[13]; const float* b4b = (const float*)d_in[14];
  const float* c1w = (const float*)d_in[15]; const float* c1b = (const float*)d_in[16];
  const float* cg1w = (const float*)d_in[17]; const float* cg1b = (const float*)d_in[18];
  const float* c2w = (const float*)d_in[19]; const float* c2b = (const float*)d_in[20];
  const float* cg2w = (const float*)d_in[21]; const float* cg2b = (const float*)d_in[22];
  const float* c3w = (const float*)d_in[23]; const float* c3b = (const float*)d_in[24];

  float* ws = (float*)d_ws;
  float* wp1b = ws; ws += 1572864;   // 512*256*12
  float* wp1c = ws; ws += 1572864;
  float* wp2b = ws; ws += 393216;    // 256*128*12
  float* wp2c = ws; ws += 393216;
  float* wp3b = ws; ws += 196608;    // 128*128*12
  float* wt4b = ws; ws += 4608;
  float* wt3c = ws; ws += 1152;
  float* t1b = ws; ws += 1605632;
  float* t1c = ws; ws += 1605632;
  float* t2b = ws; ws += 802816;
  float* t2c = ws; ws += 802816;
  float* t3b = ws; ws += 802816;
  float* P   = ws; ws += 6422528;    // partial region (aliased across layers)
  float* bbox = ws; ws += 225792;
  float* conf = ws; ws += 56448;

  wtrans_all<<<12119, 256, 0, stream>>>(b1w, c1w, b2w, c2w, b3w, b4w, c3w,
                                        wp1b, wp1c, wp2b, wp2c, wp3b, wt4b, wt3c);

  // conv1: Cin=512, Cout=256, COPT=4 (64 co/block), S=2 -> 512 blocks = 2/CU resident
  {
    const size_t sStr = (size_t)32 * 256 * 196;          // 1605632
    conv3x3_part<4><<<dim3(8, 32, 2), 256, 0, stream>>>(
        features, features, wp1b, wp1c, P, P + 2 * sStr, 512, 256, 4, 256, sStr);
    combine_gn<2><<<dim3(32, 32), 256, 0, stream>>>(
        P, P + 2 * sStr, b1b, c1b, bg1w, cg1w, bg1b, cg1b, t1b, t1c, 256, 16, sStr);
  }
  // conv2: Cin=256, Cout=128, COPT=4, S=4 -> 512 blocks
  {
    const size_t sStr = (size_t)32 * 128 * 196;          // 802816
    conv3x3_part<4><<<dim3(4, 32, 4), 256, 0, stream>>>(
        t1b, t1c, wp2b, wp2c, P, P + 4 * sStr, 256, 128, 2, 64, sStr);
    combine_gn<4><<<dim3(16, 32), 256, 0, stream>>>(
        P, P + 4 * sStr, b2b, c2b, bg2w, cg2w, bg2b, cg2b, t2b, t2c, 128, 8, sStr);
  }
  // conv3 (bbox only): Cin=128, Cout=128, COPT=4, S=8 (single chunk) -> 512 blocks
  {
    const size_t sStr = (size_t)32 * 128 * 196;
    conv3x3_part<4><<<dim3(2, 32, 8), 256, 0, stream>>>(
        t2b, t2b, wp3b, wp3b, P, P, 128, 128, 2, 16, sStr);
    combine_gn<8><<<dim3(8, 32), 256, 0, stream>>>(
        P, P, b3b, b3b, bg3w, bg3w, bg3b, bg3b, t3b, t3b, 128, 8, sStr);
  }

  heads_1x1<<<32, 256, 0, stream>>>(t3b, t2c, wt4b, wt3c, b4b, c3b, bbox, conf);
  nms_kernel<<<32, 256, 0, stream>>>(bbox, conf, (float*)d_out);
}